// Round 1
// baseline (986.895 us; speedup 1.0000x reference)
//
#include <hip/hip_runtime.h>
#include <hip/hip_bf16.h>
#include <cstdint>

#define N_NODES_C 50000
#define HIDC 128

// ---------------- init: deg=1 (self loop), cnt=0, pooled=0 ----------------
__global__ void init_kernel(float* __restrict__ deg, int* __restrict__ cnt,
                            float* __restrict__ pooled, int n_nodes, int n_pool) {
    int i = blockIdx.x * blockDim.x + threadIdx.x;
    if (i < n_nodes) { deg[i] = 1.0f; cnt[i] = 0; }
    if (i < n_pool) pooled[i] = 0.0f;
}

// ---------------- deg += edge_attr scattered to dst; count in-degree ------
__global__ void deg_count_kernel(const int* __restrict__ ei, const float* __restrict__ ea,
                                 float* __restrict__ deg, int* __restrict__ cnt, int E) {
    int e = blockIdx.x * blockDim.x + threadIdx.x;
    if (e >= E) return;
    int d = ei[E + e];           // dst row
    atomicAdd(&deg[d], ea[e]);
    atomicAdd(&cnt[d], 1);
}

// ---------------- dinv = rsqrt(deg), in place -----------------------------
__global__ void dinv_kernel(float* __restrict__ deg, int n_nodes) {
    int i = blockIdx.x * blockDim.x + threadIdx.x;
    if (i < n_nodes) deg[i] = rsqrtf(deg[i]);   // deg >= 1 always (self loop)
}

// ---------------- single-block exclusive scan of cnt -> rowptr, cursor ----
__global__ __launch_bounds__(1024) void scan_kernel(const int* __restrict__ cnt,
                                                    int* __restrict__ rowptr,
                                                    int* __restrict__ cursor, int n) {
    const int T = 1024;
    int t = threadIdx.x;
    int chunk = (n + T - 1) / T;
    int base = t * chunk;
    int sum = 0;
    for (int i = 0; i < chunk; ++i) {
        int idx = base + i;
        if (idx < n) sum += cnt[idx];
    }
    __shared__ int sh[1024];
    sh[t] = sum;
    __syncthreads();
    for (int off = 1; off < T; off <<= 1) {
        int v = (t >= off) ? sh[t - off] : 0;
        __syncthreads();
        sh[t] += v;
        __syncthreads();
    }
    int run = (t == 0) ? 0 : sh[t - 1];   // exclusive prefix
    for (int i = 0; i < chunk; ++i) {
        int idx = base + i;
        if (idx < n) { rowptr[idx] = run; cursor[idx] = run; run += cnt[idx]; }
    }
    if (t == T - 1) rowptr[n] = run;      // == E
}

// ---------------- fill CSR slots (src idx + fused norm coef) --------------
__global__ void fill_kernel(const int* __restrict__ ei, const float* __restrict__ ea,
                            const float* __restrict__ dinv, int* __restrict__ cursor,
                            int* __restrict__ csr_src, float* __restrict__ csr_coef, int E) {
    int e = blockIdx.x * blockDim.x + threadIdx.x;
    if (e >= E) return;
    int s = ei[e];
    int d = ei[E + e];
    float c = dinv[s] * ea[e] * dinv[d];
    int pos = atomicAdd(&cursor[d], 1);
    csr_src[pos] = s;
    csr_coef[pos] = c;
}

// ---------------- dense GEMM: out[n, F] = A[n, K] @ W[K, F] ---------------
template <int K, int F>
__global__ __launch_bounds__(F) void gemm_nodes(const float* __restrict__ A,
                                                const float* __restrict__ W,
                                                float* __restrict__ out) {
    int node = blockIdx.x;
    int d = threadIdx.x;          // 0..F-1
    __shared__ float row[K];
    if (d < K) row[d] = A[(size_t)node * K + d];
    __syncthreads();
    float acc = 0.f;
#pragma unroll 8
    for (int k = 0; k < K; ++k) acc += row[k] * W[k * F + d];
    out[(size_t)node * F + d] = acc;
}

// ---------------- CSR gather-aggregate + self loop + bias + ReLU ----------
// one wave per node; lane owns float2 of the 128-dim feature
__global__ __launch_bounds__(256) void agg_kernel(const float* __restrict__ h,
                                                  const int* __restrict__ rowptr,
                                                  const int* __restrict__ csr_src,
                                                  const float* __restrict__ csr_coef,
                                                  const float* __restrict__ dinv,
                                                  const float* __restrict__ bias,
                                                  float* __restrict__ out, int n_nodes) {
    int wave = threadIdx.x >> 6;
    int lane = threadIdx.x & 63;
    int node = blockIdx.x * 4 + wave;
    if (node >= n_nodes) return;
    int beg = rowptr[node];
    int end = rowptr[node + 1];
    float a0 = 0.f, a1 = 0.f;
    for (int e = beg; e < end; ++e) {
        int s = csr_src[e];
        float c = csr_coef[e];
        const float2 v = *(reinterpret_cast<const float2*>(h + (size_t)s * HIDC) + lane);
        a0 += c * v.x;
        a1 += c * v.y;
    }
    float di = dinv[node];
    float selfc = di * di;
    const float2 vn = *(reinterpret_cast<const float2*>(h + (size_t)node * HIDC) + lane);
    a0 += selfc * vn.x;
    a1 += selfc * vn.y;
    a0 = fmaxf(a0 + bias[2 * lane], 0.f);
    a1 = fmaxf(a1 + bias[2 * lane + 1], 0.f);
    float2* op = reinterpret_cast<float2*>(out + (size_t)node * HIDC) + lane;
    *op = make_float2(a0, a1);
}

// ---------------- global add pool via atomics -----------------------------
__global__ void pool_kernel(const float* __restrict__ h, const int* __restrict__ batch,
                            float* __restrict__ pooled, int n_nodes) {
    int idx = blockIdx.x * blockDim.x + threadIdx.x;
    if (idx >= n_nodes * HIDC) return;
    int node = idx >> 7;
    int d = idx & 127;
    int g = batch[node];
    atomicAdd(&pooled[g * HIDC + d], h[idx]);
}

// ---------------- fused MLP head: relu(p@Wm1+bm1)@Wm2+bm2 -----------------
__global__ __launch_bounds__(128) void mlp_kernel(const float* __restrict__ pooled,
                                                  const float* __restrict__ Wm1,
                                                  const float* __restrict__ bm1,
                                                  const float* __restrict__ Wm2,
                                                  const float* __restrict__ bm2,
                                                  float* __restrict__ out, int out_dim) {
    int g = blockIdx.x;
    int t = threadIdx.x;
    __shared__ float row[128];
    __shared__ float z[128];
    row[t] = pooled[g * 128 + t];
    __syncthreads();
    float acc = bm1[t];
#pragma unroll 8
    for (int k = 0; k < 128; ++k) acc += row[k] * Wm1[k * 128 + t];
    z[t] = fmaxf(acc, 0.f);
    __syncthreads();
    if (t < out_dim) {
        float o = bm2[t];
#pragma unroll 8
        for (int k = 0; k < 128; ++k) o += z[k] * Wm2[k * out_dim + t];
        out[g * out_dim + t] = o;
    }
}

extern "C" void kernel_launch(void* const* d_in, const int* in_sizes, int n_in,
                              void* d_out, int out_size, void* d_ws, size_t ws_size,
                              hipStream_t stream) {
    const float* x   = (const float*)d_in[0];
    const int*   ei  = (const int*)d_in[1];
    const int*   bat = (const int*)d_in[2];
    const float* ea  = (const float*)d_in[3];
    const float* W1  = (const float*)d_in[4];
    const float* b1  = (const float*)d_in[5];
    const float* W2  = (const float*)d_in[6];
    const float* b2  = (const float*)d_in[7];
    const float* Wm1 = (const float*)d_in[8];
    const float* bm1 = (const float*)d_in[9];
    const float* Wm2 = (const float*)d_in[10];
    const float* bm2 = (const float*)d_in[11];
    float* out = (float*)d_out;

    const int N = in_sizes[2];           // 50000 nodes
    const int E = in_sizes[1] / 2;       // 1.6M edges
    const int IN_DIM = in_sizes[0] / N;  // 64
    const int N_GRAPHS = 512;
    const int OUT_DIM = out_size / N_GRAPHS;  // 10

    // workspace layout (all 16B-aligned)
    char* ws = (char*)d_ws;
    size_t off = 0;
    auto alloc = [&](size_t bytes) { char* p = ws + off; off += (bytes + 255) & ~size_t(255); return p; };
    float* bufA     = (float*)alloc((size_t)N * HIDC * 4);  // h1 then h2
    float* bufB     = (float*)alloc((size_t)N * HIDC * 4);  // hr1 then hr2
    int*   csr_src  = (int*)  alloc((size_t)E * 4);
    float* csr_coef = (float*)alloc((size_t)E * 4);
    float* deg      = (float*)alloc((size_t)N * 4);         // becomes dinv
    int*   cnt      = (int*)  alloc((size_t)N * 4);
    int*   rowptr   = (int*)  alloc((size_t)(N + 1) * 4);
    int*   cursor   = (int*)  alloc((size_t)N * 4);
    float* pooled   = (float*)alloc((size_t)N_GRAPHS * HIDC * 4);

    const int B = 256;
    int gN  = (N + B - 1) / B;
    int gE  = (E + B - 1) / B;
    int gNP = ((N > N_GRAPHS * HIDC ? N : N_GRAPHS * HIDC) + B - 1) / B;

    // 1. init
    init_kernel<<<gNP, B, 0, stream>>>(deg, cnt, pooled, N, N_GRAPHS * HIDC);
    // 2. degree + in-degree count
    deg_count_kernel<<<gE, B, 0, stream>>>(ei, ea, deg, cnt, E);
    // 3. dinv
    dinv_kernel<<<gN, B, 0, stream>>>(deg, N);
    // 4. exclusive scan -> rowptr, cursor
    scan_kernel<<<1, 1024, 0, stream>>>(cnt, rowptr, cursor, N);
    // 5. CSR fill with fused norm coefficient
    fill_kernel<<<gE, B, 0, stream>>>(ei, ea, deg, cursor, csr_src, csr_coef, E);
    // 6. h1 = x @ W1
    gemm_nodes<64, 128><<<N, 128, 0, stream>>>(x, W1, bufA);
    // 7. hr1 = relu(aggregate(h1) + b1)
    agg_kernel<<<(N + 3) / 4, 256, 0, stream>>>(bufA, rowptr, csr_src, csr_coef, deg, b1, bufB, N);
    // 8. h2 = hr1 @ W2
    gemm_nodes<128, 128><<<N, 128, 0, stream>>>(bufB, W2, bufA);
    // 9. hr2 = relu(aggregate(h2) + b2)
    agg_kernel<<<(N + 3) / 4, 256, 0, stream>>>(bufA, rowptr, csr_src, csr_coef, deg, b2, bufB, N);
    // 10. pooled[g] += hr2[node]
    pool_kernel<<<(N * HIDC + B - 1) / B, B, 0, stream>>>(bufB, bat, pooled, N);
    // 11. MLP head
    mlp_kernel<<<N_GRAPHS, 128, 0, stream>>>(pooled, Wm1, bm1, Wm2, bm2, out, OUT_DIM);
}

// Round 2
// 836.158 us; speedup vs baseline: 1.1803x; 1.1803x over previous
//
#include <hip/hip_runtime.h>
#include <hip/hip_bf16.h>
#include <cstdint>

#define HIDC 128

// ---------------- init: deg=1 (self loop), cnt=0 --------------------------
__global__ void init_kernel(float* __restrict__ deg, int* __restrict__ cnt, int n_nodes) {
    int i = blockIdx.x * blockDim.x + threadIdx.x;
    if (i < n_nodes) { deg[i] = 1.0f; cnt[i] = 0; }
}

// ---------------- deg += edge_attr scattered to dst; count in-degree ------
__global__ void deg_count_kernel(const int* __restrict__ ei, const float* __restrict__ ea,
                                 float* __restrict__ deg, int* __restrict__ cnt, int E) {
    int e = blockIdx.x * blockDim.x + threadIdx.x;
    if (e >= E) return;
    int d = ei[E + e];           // dst row
    atomicAdd(&deg[d], ea[e]);
    atomicAdd(&cnt[d], 1);
}

// ---------------- dinv = rsqrt(deg), in place -----------------------------
__global__ void dinv_kernel(float* __restrict__ deg, int n_nodes) {
    int i = blockIdx.x * blockDim.x + threadIdx.x;
    if (i < n_nodes) deg[i] = rsqrtf(deg[i]);   // deg >= 1 always (self loop)
}

// ---------------- single-block exclusive scan of cnt -> rowptr, cursor ----
__global__ __launch_bounds__(1024) void scan_kernel(const int* __restrict__ cnt,
                                                    int* __restrict__ rowptr,
                                                    int* __restrict__ cursor, int n) {
    const int T = 1024;
    int t = threadIdx.x;
    int chunk = (n + T - 1) / T;
    int base = t * chunk;
    int sum = 0;
    for (int i = 0; i < chunk; ++i) {
        int idx = base + i;
        if (idx < n) sum += cnt[idx];
    }
    __shared__ int sh[1024];
    sh[t] = sum;
    __syncthreads();
    for (int off = 1; off < T; off <<= 1) {
        int v = (t >= off) ? sh[t - off] : 0;
        __syncthreads();
        sh[t] += v;
        __syncthreads();
    }
    int run = (t == 0) ? 0 : sh[t - 1];   // exclusive prefix
    for (int i = 0; i < chunk; ++i) {
        int idx = base + i;
        if (idx < n) { rowptr[idx] = run; cursor[idx] = run; run += cnt[idx]; }
    }
    if (t == T - 1) rowptr[n] = run;      // == E
}

// ---------------- fill CSR slots (src idx + fused norm coef) --------------
__global__ void fill_kernel(const int* __restrict__ ei, const float* __restrict__ ea,
                            const float* __restrict__ dinv, int* __restrict__ cursor,
                            int* __restrict__ csr_src, float* __restrict__ csr_coef, int E) {
    int e = blockIdx.x * blockDim.x + threadIdx.x;
    if (e >= E) return;
    int s = ei[e];
    int d = ei[E + e];
    float c = dinv[s] * ea[e] * dinv[d];
    int pos = atomicAdd(&cursor[d], 1);
    csr_src[pos] = s;
    csr_coef[pos] = c;
}

// ---------------- tiled GEMM: out[n,128] = A[n,K] @ W[K,128] --------------
// 16 nodes per block; W staged in LDS once per block.
template <int K>
__global__ __launch_bounds__(256) void gemm_tiled(const float* __restrict__ A,
                                                  const float* __restrict__ W,
                                                  float* __restrict__ out, int n_nodes) {
    __shared__ float sW[K * 128];
    __shared__ float sX[16 * K];
    int t = threadIdx.x;
    int nodeBase = blockIdx.x * 16;
    for (int i = t; i < K * 128; i += 256) sW[i] = W[i];
    // 16 rows of A are contiguous: coalesced bulk load
    int nAvail = n_nodes - nodeBase; if (nAvail > 16) nAvail = 16;
    for (int i = t; i < nAvail * K; i += 256) sX[i] = A[(size_t)nodeBase * K + i];
    __syncthreads();
    int d = t & 127;
    for (int ni = (t >> 7); ni < nAvail; ni += 2) {
        float acc = 0.f;
#pragma unroll
        for (int k = 0; k < K; ++k) acc += sX[ni * K + k] * sW[k * 128 + d];
        out[(size_t)(nodeBase + ni) * 128 + d] = acc;
    }
}

// ---------------- CSR gather-aggregate + self loop + bias + ReLU ----------
// one wave per node; lane owns float2 of the 128-dim feature; edge loop
// unrolled x8 so 8 gathers are in flight per wave (latency hiding).
__global__ __launch_bounds__(256) void agg_kernel(const float* __restrict__ h,
                                                  const int* __restrict__ rowptr,
                                                  const int* __restrict__ csr_src,
                                                  const float* __restrict__ csr_coef,
                                                  const float* __restrict__ dinv,
                                                  const float* __restrict__ bias,
                                                  float* __restrict__ out, int n_nodes) {
    int wave = threadIdx.x >> 6;
    int lane = threadIdx.x & 63;
    int node = blockIdx.x * 4 + wave;
    if (node >= n_nodes) return;
    int beg = rowptr[node];
    int end = rowptr[node + 1];
    float a0 = 0.f, a1 = 0.f;
    int e = beg;
    for (; e + 8 <= end; e += 8) {
        int   s0 = csr_src[e],  s1 = csr_src[e+1], s2 = csr_src[e+2], s3 = csr_src[e+3];
        int   s4 = csr_src[e+4], s5 = csr_src[e+5], s6 = csr_src[e+6], s7 = csr_src[e+7];
        float c0 = csr_coef[e],  c1 = csr_coef[e+1], c2 = csr_coef[e+2], c3 = csr_coef[e+3];
        float c4 = csr_coef[e+4], c5 = csr_coef[e+5], c6 = csr_coef[e+6], c7 = csr_coef[e+7];
        float2 v0 = *(reinterpret_cast<const float2*>(h + (size_t)s0 * HIDC) + lane);
        float2 v1 = *(reinterpret_cast<const float2*>(h + (size_t)s1 * HIDC) + lane);
        float2 v2 = *(reinterpret_cast<const float2*>(h + (size_t)s2 * HIDC) + lane);
        float2 v3 = *(reinterpret_cast<const float2*>(h + (size_t)s3 * HIDC) + lane);
        float2 v4 = *(reinterpret_cast<const float2*>(h + (size_t)s4 * HIDC) + lane);
        float2 v5 = *(reinterpret_cast<const float2*>(h + (size_t)s5 * HIDC) + lane);
        float2 v6 = *(reinterpret_cast<const float2*>(h + (size_t)s6 * HIDC) + lane);
        float2 v7 = *(reinterpret_cast<const float2*>(h + (size_t)s7 * HIDC) + lane);
        a0 += c0 * v0.x; a1 += c0 * v0.y;
        a0 += c1 * v1.x; a1 += c1 * v1.y;
        a0 += c2 * v2.x; a1 += c2 * v2.y;
        a0 += c3 * v3.x; a1 += c3 * v3.y;
        a0 += c4 * v4.x; a1 += c4 * v4.y;
        a0 += c5 * v5.x; a1 += c5 * v5.y;
        a0 += c6 * v6.x; a1 += c6 * v6.y;
        a0 += c7 * v7.x; a1 += c7 * v7.y;
    }
    for (; e < end; ++e) {
        int s = csr_src[e];
        float c = csr_coef[e];
        float2 v = *(reinterpret_cast<const float2*>(h + (size_t)s * HIDC) + lane);
        a0 += c * v.x; a1 += c * v.y;
    }
    float di = dinv[node];
    float selfc = di * di;
    float2 vn = *(reinterpret_cast<const float2*>(h + (size_t)node * HIDC) + lane);
    a0 += selfc * vn.x;
    a1 += selfc * vn.y;
    float2 bb = *(reinterpret_cast<const float2*>(bias) + lane);
    a0 = fmaxf(a0 + bb.x, 0.f);
    a1 = fmaxf(a1 + bb.y, 0.f);
    float2* op = reinterpret_cast<float2*>(out + (size_t)node * HIDC) + lane;
    *op = make_float2(a0, a1);
}

// ---------------- gptr[g] = lower_bound(batch, g) (batch is sorted) -------
__global__ void gptr_kernel(const int* __restrict__ batch, int* __restrict__ gptr,
                            int n_nodes, int n_graphs) {
    int g = blockIdx.x * blockDim.x + threadIdx.x;
    if (g > n_graphs) return;
    int lo = 0, hi = n_nodes;
    while (lo < hi) { int mid = (lo + hi) >> 1; if (batch[mid] < g) lo = mid + 1; else hi = mid; }
    gptr[g] = lo;
}

// ---------------- segmented pool: one wave per graph, no atomics ----------
__global__ __launch_bounds__(256) void pool_seg_kernel(const float* __restrict__ h,
                                                       const int* __restrict__ gptr,
                                                       float* __restrict__ pooled,
                                                       int n_graphs) {
    int wave = threadIdx.x >> 6;
    int lane = threadIdx.x & 63;
    int g = blockIdx.x * 4 + wave;
    if (g >= n_graphs) return;
    int beg = gptr[g], end = gptr[g + 1];
    float a0 = 0.f, a1 = 0.f;
    for (int i = beg; i < end; ++i) {
        float2 v = *(reinterpret_cast<const float2*>(h + (size_t)i * HIDC) + lane);
        a0 += v.x; a1 += v.y;
    }
    float2* op = reinterpret_cast<float2*>(pooled + (size_t)g * HIDC) + lane;
    *op = make_float2(a0, a1);
}

// ---------------- fused MLP head: relu(p@Wm1+bm1)@Wm2+bm2 -----------------
__global__ __launch_bounds__(128) void mlp_kernel(const float* __restrict__ pooled,
                                                  const float* __restrict__ Wm1,
                                                  const float* __restrict__ bm1,
                                                  const float* __restrict__ Wm2,
                                                  const float* __restrict__ bm2,
                                                  float* __restrict__ out, int out_dim) {
    int g = blockIdx.x;
    int t = threadIdx.x;
    __shared__ float row[128];
    __shared__ float z[128];
    row[t] = pooled[g * 128 + t];
    __syncthreads();
    float acc = bm1[t];
#pragma unroll 8
    for (int k = 0; k < 128; ++k) acc += row[k] * Wm1[k * 128 + t];
    z[t] = fmaxf(acc, 0.f);
    __syncthreads();
    if (t < out_dim) {
        float o = bm2[t];
#pragma unroll 8
        for (int k = 0; k < 128; ++k) o += z[k] * Wm2[k * out_dim + t];
        out[g * out_dim + t] = o;
    }
}

extern "C" void kernel_launch(void* const* d_in, const int* in_sizes, int n_in,
                              void* d_out, int out_size, void* d_ws, size_t ws_size,
                              hipStream_t stream) {
    const float* x   = (const float*)d_in[0];
    const int*   ei  = (const int*)d_in[1];
    const int*   bat = (const int*)d_in[2];
    const float* ea  = (const float*)d_in[3];
    const float* W1  = (const float*)d_in[4];
    const float* b1  = (const float*)d_in[5];
    const float* W2  = (const float*)d_in[6];
    const float* b2  = (const float*)d_in[7];
    const float* Wm1 = (const float*)d_in[8];
    const float* bm1 = (const float*)d_in[9];
    const float* Wm2 = (const float*)d_in[10];
    const float* bm2 = (const float*)d_in[11];
    float* out = (float*)d_out;

    const int N = in_sizes[2];           // 50000 nodes
    const int E = in_sizes[1] / 2;       // 1.6M edges
    const int N_GRAPHS = 512;
    const int OUT_DIM = out_size / N_GRAPHS;  // 10

    // workspace layout (all 256B-aligned)
    char* ws = (char*)d_ws;
    size_t off = 0;
    auto alloc = [&](size_t bytes) { char* p = ws + off; off += (bytes + 255) & ~size_t(255); return p; };
    float* bufA     = (float*)alloc((size_t)N * HIDC * 4);  // h1 then h2
    float* bufB     = (float*)alloc((size_t)N * HIDC * 4);  // hr1 then hr2
    int*   csr_src  = (int*)  alloc((size_t)E * 4);
    float* csr_coef = (float*)alloc((size_t)E * 4);
    float* deg      = (float*)alloc((size_t)N * 4);         // becomes dinv
    int*   cnt      = (int*)  alloc((size_t)N * 4);
    int*   rowptr   = (int*)  alloc((size_t)(N + 1) * 4);
    int*   cursor   = (int*)  alloc((size_t)N * 4);
    int*   gptr     = (int*)  alloc((size_t)(N_GRAPHS + 1) * 4);
    float* pooled   = (float*)alloc((size_t)N_GRAPHS * HIDC * 4);

    const int B = 256;
    int gN = (N + B - 1) / B;
    int gE = (E + B - 1) / B;

    // 1. init
    init_kernel<<<gN, B, 0, stream>>>(deg, cnt, N);
    // 2. degree + in-degree count
    deg_count_kernel<<<gE, B, 0, stream>>>(ei, ea, deg, cnt, E);
    // 3. dinv
    dinv_kernel<<<gN, B, 0, stream>>>(deg, N);
    // 4. exclusive scan -> rowptr, cursor
    scan_kernel<<<1, 1024, 0, stream>>>(cnt, rowptr, cursor, N);
    // 5. CSR fill with fused norm coefficient
    fill_kernel<<<gE, B, 0, stream>>>(ei, ea, deg, cursor, csr_src, csr_coef, E);
    // 6. h1 = x @ W1
    gemm_tiled<64><<<(N + 15) / 16, 256, 0, stream>>>(x, W1, bufA, N);
    // 7. hr1 = relu(aggregate(h1) + b1)
    agg_kernel<<<(N + 3) / 4, 256, 0, stream>>>(bufA, rowptr, csr_src, csr_coef, deg, b1, bufB, N);
    // 8. h2 = hr1 @ W2
    gemm_tiled<128><<<(N + 15) / 16, 256, 0, stream>>>(bufB, W2, bufA, N);
    // 9. hr2 = relu(aggregate(h2) + b2)
    agg_kernel<<<(N + 3) / 4, 256, 0, stream>>>(bufA, rowptr, csr_src, csr_coef, deg, b2, bufB, N);
    // 10. gptr via binary search on sorted batch
    gptr_kernel<<<3, 256, 0, stream>>>(bat, gptr, N, N_GRAPHS);
    // 11. segmented pool (no atomics)
    pool_seg_kernel<<<(N_GRAPHS + 3) / 4, 256, 0, stream>>>(bufB, gptr, pooled, N_GRAPHS);
    // 12. MLP head
    mlp_kernel<<<N_GRAPHS, 128, 0, stream>>>(pooled, Wm1, bm1, Wm2, bm2, out, OUT_DIM);
}

// Round 3
// 600.432 us; speedup vs baseline: 1.6436x; 1.3926x over previous
//
#include <hip/hip_runtime.h>
#include <hip/hip_bf16.h>
#include <cstdint>

#define HIDC 128
#define FIXSCALE 4194304.0f        // 2^22
#define FIXINV   (1.0f / 4194304.0f)

// ---------------- zero degcnt (u64 per node) ------------------------------
__global__ void init_kernel(unsigned long long* __restrict__ degcnt, int n_nodes) {
    int i = blockIdx.x * blockDim.x + threadIdx.x;
    if (i < n_nodes) degcnt[i] = 0ull;
}

// ---------------- one u64 atomic per edge: cnt<<32 | fixpoint(ea) ---------
__global__ void deg_count_kernel(const int* __restrict__ ei, const float* __restrict__ ea,
                                 unsigned long long* __restrict__ degcnt, int E) {
    int e = blockIdx.x * blockDim.x + threadIdx.x;
    if (e >= E) return;
    int d = ei[E + e];                         // dst
    unsigned int fx = (unsigned int)(ea[e] * FIXSCALE + 0.5f);
    unsigned long long pack = (1ull << 32) | (unsigned long long)fx;
    atomicAdd(&degcnt[d], pack);
}

// ---------------- scan phase A: dinv + per-block count sums ---------------
__global__ __launch_bounds__(256) void dinv_blocksum_kernel(const unsigned long long* __restrict__ degcnt,
                                                            float* __restrict__ dinv,
                                                            int* __restrict__ blocksum, int n_nodes) {
    __shared__ int sh[256];
    int t = threadIdx.x;
    int i = blockIdx.x * 256 + t;
    int cnt = 0;
    if (i < n_nodes) {
        unsigned long long v = degcnt[i];
        cnt = (int)(v >> 32);
        float deg = 1.0f + (float)(unsigned int)(v & 0xffffffffull) * FIXINV;
        dinv[i] = rsqrtf(deg);
    }
    sh[t] = cnt;
    __syncthreads();
    for (int off = 128; off > 0; off >>= 1) {
        if (t < off) sh[t] += sh[t + off];
        __syncthreads();
    }
    if (t == 0) blocksum[blockIdx.x] = sh[0];
}

// ---------------- scan phase B: exclusive scan of block sums (1 block) ----
__global__ __launch_bounds__(256) void scan_blocksums_kernel(const int* __restrict__ blocksum,
                                                             int* __restrict__ blockoff, int nb) {
    __shared__ int sh[256];
    int t = threadIdx.x;
    int v = (t < nb) ? blocksum[t] : 0;
    sh[t] = v;
    __syncthreads();
    for (int off = 1; off < 256; off <<= 1) {
        int u = (t >= off) ? sh[t - off] : 0;
        __syncthreads();
        sh[t] += u;
        __syncthreads();
    }
    if (t < nb) blockoff[t] = sh[t] - v;       // exclusive
}

// ---------------- scan phase C: rowptr + cursor ---------------------------
__global__ __launch_bounds__(256) void rowptr_kernel(const unsigned long long* __restrict__ degcnt,
                                                     const int* __restrict__ blockoff,
                                                     int* __restrict__ rowptr,
                                                     int* __restrict__ cursor, int n_nodes) {
    __shared__ int sh[256];
    int t = threadIdx.x;
    int i = blockIdx.x * 256 + t;
    int cnt = (i < n_nodes) ? (int)(degcnt[i] >> 32) : 0;
    sh[t] = cnt;
    __syncthreads();
    for (int off = 1; off < 256; off <<= 1) {
        int u = (t >= off) ? sh[t - off] : 0;
        __syncthreads();
        sh[t] += u;
        __syncthreads();
    }
    if (i < n_nodes) {
        int excl = blockoff[blockIdx.x] + sh[t] - cnt;
        rowptr[i] = excl;
        cursor[i] = excl;
        if (i == n_nodes - 1) rowptr[n_nodes] = excl + cnt;
    }
}

// ---------------- fill CSR slots: one 8B packed write per edge ------------
__global__ void fill_kernel(const int* __restrict__ ei, const float* __restrict__ ea,
                            const float* __restrict__ dinv, int* __restrict__ cursor,
                            int2* __restrict__ csr, int E) {
    int e = blockIdx.x * blockDim.x + threadIdx.x;
    if (e >= E) return;
    int s = ei[e];
    int d = ei[E + e];
    float c = dinv[s] * ea[e] * dinv[d];
    int pos = atomicAdd(&cursor[d], 1);
    csr[pos] = make_int2(s, __float_as_int(c));
}

// ---------------- tiled GEMM: out[n,128] = A[n,K] @ W[K,128] --------------
template <int K>
__global__ __launch_bounds__(256) void gemm_tiled(const float* __restrict__ A,
                                                  const float* __restrict__ W,
                                                  float* __restrict__ out, int n_nodes) {
    __shared__ float sW[K * 128];
    __shared__ float sX[16 * K];
    int t = threadIdx.x;
    int nodeBase = blockIdx.x * 16;
    for (int i = t; i < K * 128; i += 256) sW[i] = W[i];
    int nAvail = n_nodes - nodeBase; if (nAvail > 16) nAvail = 16;
    for (int i = t; i < nAvail * K; i += 256) sX[i] = A[(size_t)nodeBase * K + i];
    __syncthreads();
    int d = t & 127;
    for (int ni = (t >> 7); ni < nAvail; ni += 2) {
        float acc = 0.f;
#pragma unroll
        for (int k = 0; k < K; ++k) acc += sX[ni * K + k] * sW[k * 128 + d];
        out[(size_t)(nodeBase + ni) * 128 + d] = acc;
    }
}

// ---------------- CSR gather-aggregate + self loop + bias + ReLU ----------
__global__ __launch_bounds__(256) void agg_kernel(const float* __restrict__ h,
                                                  const int* __restrict__ rowptr,
                                                  const int2* __restrict__ csr,
                                                  const float* __restrict__ dinv,
                                                  const float* __restrict__ bias,
                                                  float* __restrict__ out, int n_nodes) {
    int wave = threadIdx.x >> 6;
    int lane = threadIdx.x & 63;
    int node = blockIdx.x * 4 + wave;
    if (node >= n_nodes) return;
    int beg = rowptr[node];
    int end = rowptr[node + 1];
    float a0 = 0.f, a1 = 0.f;
    int e = beg;
    for (; e + 8 <= end; e += 8) {
        int2 p0 = csr[e],   p1 = csr[e+1], p2 = csr[e+2], p3 = csr[e+3];
        int2 p4 = csr[e+4], p5 = csr[e+5], p6 = csr[e+6], p7 = csr[e+7];
        float2 v0 = *(reinterpret_cast<const float2*>(h + (size_t)p0.x * HIDC) + lane);
        float2 v1 = *(reinterpret_cast<const float2*>(h + (size_t)p1.x * HIDC) + lane);
        float2 v2 = *(reinterpret_cast<const float2*>(h + (size_t)p2.x * HIDC) + lane);
        float2 v3 = *(reinterpret_cast<const float2*>(h + (size_t)p3.x * HIDC) + lane);
        float2 v4 = *(reinterpret_cast<const float2*>(h + (size_t)p4.x * HIDC) + lane);
        float2 v5 = *(reinterpret_cast<const float2*>(h + (size_t)p5.x * HIDC) + lane);
        float2 v6 = *(reinterpret_cast<const float2*>(h + (size_t)p6.x * HIDC) + lane);
        float2 v7 = *(reinterpret_cast<const float2*>(h + (size_t)p7.x * HIDC) + lane);
        float c0 = __int_as_float(p0.y), c1 = __int_as_float(p1.y);
        float c2 = __int_as_float(p2.y), c3 = __int_as_float(p3.y);
        float c4 = __int_as_float(p4.y), c5 = __int_as_float(p5.y);
        float c6 = __int_as_float(p6.y), c7 = __int_as_float(p7.y);
        a0 += c0 * v0.x; a1 += c0 * v0.y;
        a0 += c1 * v1.x; a1 += c1 * v1.y;
        a0 += c2 * v2.x; a1 += c2 * v2.y;
        a0 += c3 * v3.x; a1 += c3 * v3.y;
        a0 += c4 * v4.x; a1 += c4 * v4.y;
        a0 += c5 * v5.x; a1 += c5 * v5.y;
        a0 += c6 * v6.x; a1 += c6 * v6.y;
        a0 += c7 * v7.x; a1 += c7 * v7.y;
    }
    for (; e < end; ++e) {
        int2 p = csr[e];
        float c = __int_as_float(p.y);
        float2 v = *(reinterpret_cast<const float2*>(h + (size_t)p.x * HIDC) + lane);
        a0 += c * v.x; a1 += c * v.y;
    }
    float di = dinv[node];
    float selfc = di * di;
    float2 vn = *(reinterpret_cast<const float2*>(h + (size_t)node * HIDC) + lane);
    a0 += selfc * vn.x;
    a1 += selfc * vn.y;
    float2 bb = *(reinterpret_cast<const float2*>(bias) + lane);
    a0 = fmaxf(a0 + bb.x, 0.f);
    a1 = fmaxf(a1 + bb.y, 0.f);
    float2* op = reinterpret_cast<float2*>(out + (size_t)node * HIDC) + lane;
    *op = make_float2(a0, a1);
}

// ---------------- gptr[g] = lower_bound(batch, g) (batch is sorted) -------
__global__ void gptr_kernel(const int* __restrict__ batch, int* __restrict__ gptr,
                            int n_nodes, int n_graphs) {
    int g = blockIdx.x * blockDim.x + threadIdx.x;
    if (g > n_graphs) return;
    int lo = 0, hi = n_nodes;
    while (lo < hi) { int mid = (lo + hi) >> 1; if (batch[mid] < g) lo = mid + 1; else hi = mid; }
    gptr[g] = lo;
}

// ---------------- segmented pool: one wave per graph, no atomics ----------
__global__ __launch_bounds__(256) void pool_seg_kernel(const float* __restrict__ h,
                                                       const int* __restrict__ gptr,
                                                       float* __restrict__ pooled,
                                                       int n_graphs) {
    int wave = threadIdx.x >> 6;
    int lane = threadIdx.x & 63;
    int g = blockIdx.x * 4 + wave;
    if (g >= n_graphs) return;
    int beg = gptr[g], end = gptr[g + 1];
    float a0 = 0.f, a1 = 0.f;
    for (int i = beg; i < end; ++i) {
        float2 v = *(reinterpret_cast<const float2*>(h + (size_t)i * HIDC) + lane);
        a0 += v.x; a1 += v.y;
    }
    float2* op = reinterpret_cast<float2*>(pooled + (size_t)g * HIDC) + lane;
    *op = make_float2(a0, a1);
}

// ---------------- fused MLP head: relu(p@Wm1+bm1)@Wm2+bm2 -----------------
__global__ __launch_bounds__(128) void mlp_kernel(const float* __restrict__ pooled,
                                                  const float* __restrict__ Wm1,
                                                  const float* __restrict__ bm1,
                                                  const float* __restrict__ Wm2,
                                                  const float* __restrict__ bm2,
                                                  float* __restrict__ out, int out_dim) {
    int g = blockIdx.x;
    int t = threadIdx.x;
    __shared__ float row[128];
    __shared__ float z[128];
    row[t] = pooled[g * 128 + t];
    __syncthreads();
    float acc = bm1[t];
#pragma unroll 8
    for (int k = 0; k < 128; ++k) acc += row[k] * Wm1[k * 128 + t];
    z[t] = fmaxf(acc, 0.f);
    __syncthreads();
    if (t < out_dim) {
        float o = bm2[t];
#pragma unroll 8
        for (int k = 0; k < 128; ++k) o += z[k] * Wm2[k * out_dim + t];
        out[g * out_dim + t] = o;
    }
}

extern "C" void kernel_launch(void* const* d_in, const int* in_sizes, int n_in,
                              void* d_out, int out_size, void* d_ws, size_t ws_size,
                              hipStream_t stream) {
    const float* x   = (const float*)d_in[0];
    const int*   ei  = (const int*)d_in[1];
    const int*   bat = (const int*)d_in[2];
    const float* ea  = (const float*)d_in[3];
    const float* W1  = (const float*)d_in[4];
    const float* b1  = (const float*)d_in[5];
    const float* W2  = (const float*)d_in[6];
    const float* b2  = (const float*)d_in[7];
    const float* Wm1 = (const float*)d_in[8];
    const float* bm1 = (const float*)d_in[9];
    const float* Wm2 = (const float*)d_in[10];
    const float* bm2 = (const float*)d_in[11];
    float* out = (float*)d_out;

    const int N = in_sizes[2];           // 50000 nodes
    const int E = in_sizes[1] / 2;       // 1.6M edges
    const int N_GRAPHS = 512;
    const int OUT_DIM = out_size / N_GRAPHS;  // 10

    // workspace layout (all 256B-aligned)
    char* ws = (char*)d_ws;
    size_t off = 0;
    auto alloc = [&](size_t bytes) { char* p = ws + off; off += (bytes + 255) & ~size_t(255); return p; };
    float*  bufA    = (float*)alloc((size_t)N * HIDC * 4);   // h1 then h2
    float*  bufB    = (float*)alloc((size_t)N * HIDC * 4);   // hr1 then hr2
    int2*   csr     = (int2*) alloc((size_t)E * 8);
    unsigned long long* degcnt = (unsigned long long*)alloc((size_t)N * 8);
    float*  dinv    = (float*)alloc((size_t)N * 4);
    int*    rowptr  = (int*)  alloc((size_t)(N + 1) * 4);
    int*    cursor  = (int*)  alloc((size_t)N * 4);
    int*    blocksum= (int*)  alloc(1024);
    int*    blockoff= (int*)  alloc(1024);
    int*    gptr    = (int*)  alloc((size_t)(N_GRAPHS + 1) * 4);
    float*  pooled  = (float*)alloc((size_t)N_GRAPHS * HIDC * 4);

    const int B = 256;
    int gN = (N + B - 1) / B;            // 196 blocks
    int gE = (E + B - 1) / B;

    // 1. zero degcnt
    init_kernel<<<gN, B, 0, stream>>>(degcnt, N);
    // 2. packed degree+count (one u64 atomic per edge)
    deg_count_kernel<<<gE, B, 0, stream>>>(ei, ea, degcnt, E);
    // 3a. dinv + block sums
    dinv_blocksum_kernel<<<gN, B, 0, stream>>>(degcnt, dinv, blocksum, N);
    // 3b. scan block sums
    scan_blocksums_kernel<<<1, 256, 0, stream>>>(blocksum, blockoff, gN);
    // 3c. rowptr + cursor
    rowptr_kernel<<<gN, B, 0, stream>>>(degcnt, blockoff, rowptr, cursor, N);
    // 4. CSR fill (packed int2 per edge)
    fill_kernel<<<gE, B, 0, stream>>>(ei, ea, dinv, cursor, csr, E);
    // 5. h1 = x @ W1
    gemm_tiled<64><<<(N + 15) / 16, 256, 0, stream>>>(x, W1, bufA, N);
    // 6. hr1 = relu(aggregate(h1) + b1)
    agg_kernel<<<(N + 3) / 4, 256, 0, stream>>>(bufA, rowptr, csr, dinv, b1, bufB, N);
    // 7. h2 = hr1 @ W2
    gemm_tiled<128><<<(N + 15) / 16, 256, 0, stream>>>(bufB, W2, bufA, N);
    // 8. hr2 = relu(aggregate(h2) + b2)
    agg_kernel<<<(N + 3) / 4, 256, 0, stream>>>(bufA, rowptr, csr, dinv, b2, bufB, N);
    // 9. gptr via binary search on sorted batch
    gptr_kernel<<<3, 256, 0, stream>>>(bat, gptr, N, N_GRAPHS);
    // 10. segmented pool (no atomics)
    pool_seg_kernel<<<(N_GRAPHS + 3) / 4, 256, 0, stream>>>(bufB, gptr, pooled, N_GRAPHS);
    // 11. MLP head
    mlp_kernel<<<N_GRAPHS, 128, 0, stream>>>(pooled, Wm1, bm1, Wm2, bm2, out, OUT_DIM);
}

// Round 4
// 442.363 us; speedup vs baseline: 2.2310x; 1.3573x over previous
//
#include <hip/hip_runtime.h>
#include <hip/hip_bf16.h>
#include <hip/hip_fp16.h>
#include <cstdint>

#define HIDC 128
#define FIXSCALE 4194304.0f        // 2^22
#define FIXINV   (1.0f / 4194304.0f)

// ---------------- zero degcnt (u64 per node) ------------------------------
__global__ void init_kernel(unsigned long long* __restrict__ degcnt, int n_nodes) {
    int i = blockIdx.x * blockDim.x + threadIdx.x;
    if (i < n_nodes) degcnt[i] = 0ull;
}

// ------ hist: one u64 atomic per edge; returned old value gives rank ------
__global__ void hist_kernel(const int* __restrict__ ei, const float* __restrict__ ea,
                            unsigned long long* __restrict__ degcnt,
                            int* __restrict__ rank, int E) {
    int e = blockIdx.x * blockDim.x + threadIdx.x;
    if (e >= E) return;
    int d = ei[E + e];                         // dst
    unsigned int fx = (unsigned int)(ea[e] * FIXSCALE + 0.5f);
    unsigned long long pack = (1ull << 32) | (unsigned long long)fx;
    unsigned long long old = atomicAdd(&degcnt[d], pack);
    rank[e] = (int)(old >> 32);
}

// ---------------- scan phase A: dinv + per-block count sums ---------------
__global__ __launch_bounds__(256) void dinv_blocksum_kernel(const unsigned long long* __restrict__ degcnt,
                                                            float* __restrict__ dinv,
                                                            int* __restrict__ blocksum, int n_nodes) {
    __shared__ int sh[256];
    int t = threadIdx.x;
    int i = blockIdx.x * 256 + t;
    int cnt = 0;
    if (i < n_nodes) {
        unsigned long long v = degcnt[i];
        cnt = (int)(v >> 32);
        float deg = 1.0f + (float)(unsigned int)(v & 0xffffffffull) * FIXINV;
        dinv[i] = rsqrtf(deg);
    }
    sh[t] = cnt;
    __syncthreads();
    for (int off = 128; off > 0; off >>= 1) {
        if (t < off) sh[t] += sh[t + off];
        __syncthreads();
    }
    if (t == 0) blocksum[blockIdx.x] = sh[0];
}

// ---------------- scan phase B: exclusive scan of block sums (1 block) ----
__global__ __launch_bounds__(256) void scan_blocksums_kernel(const int* __restrict__ blocksum,
                                                             int* __restrict__ blockoff, int nb) {
    __shared__ int sh[256];
    int t = threadIdx.x;
    int v = (t < nb) ? blocksum[t] : 0;
    sh[t] = v;
    __syncthreads();
    for (int off = 1; off < 256; off <<= 1) {
        int u = (t >= off) ? sh[t - off] : 0;
        __syncthreads();
        sh[t] += u;
        __syncthreads();
    }
    if (t < nb) blockoff[t] = sh[t] - v;       // exclusive
}

// ---------------- scan phase C: rowptr ------------------------------------
__global__ __launch_bounds__(256) void rowptr_kernel(const unsigned long long* __restrict__ degcnt,
                                                     const int* __restrict__ blockoff,
                                                     int* __restrict__ rowptr, int n_nodes) {
    __shared__ int sh[256];
    int t = threadIdx.x;
    int i = blockIdx.x * 256 + t;
    int cnt = (i < n_nodes) ? (int)(degcnt[i] >> 32) : 0;
    sh[t] = cnt;
    __syncthreads();
    for (int off = 1; off < 256; off <<= 1) {
        int u = (t >= off) ? sh[t - off] : 0;
        __syncthreads();
        sh[t] += u;
        __syncthreads();
    }
    if (i < n_nodes) {
        int excl = blockoff[blockIdx.x] + sh[t] - cnt;
        rowptr[i] = excl;
        if (i == n_nodes - 1) rowptr[n_nodes] = excl + cnt;
    }
}

// ------ fill CSR: atomic-free scatter via rowptr[d] + rank[e] -------------
__global__ void fill_kernel(const int* __restrict__ ei, const float* __restrict__ ea,
                            const float* __restrict__ dinv, const int* __restrict__ rowptr,
                            const int* __restrict__ rank,
                            int2* __restrict__ csr, int E) {
    int e = blockIdx.x * blockDim.x + threadIdx.x;
    if (e >= E) return;
    int s = ei[e];
    int d = ei[E + e];
    float c = dinv[s] * ea[e] * dinv[d];
    int pos = rowptr[d] + rank[e];
    csr[pos] = make_int2(s, __float_as_int(c));
}

// ------ tiled GEMM: out[n,128] = A[n,K] @ W[K,128], fp16 output -----------
template <int K>
__global__ __launch_bounds__(256) void gemm_tiled(const float* __restrict__ A,
                                                  const float* __restrict__ W,
                                                  __half* __restrict__ out, int n_nodes) {
    __shared__ float sW[K * 128];
    __shared__ float sX[16 * K];
    int t = threadIdx.x;
    int nodeBase = blockIdx.x * 16;
    for (int i = t; i < K * 128; i += 256) sW[i] = W[i];
    int nAvail = n_nodes - nodeBase; if (nAvail > 16) nAvail = 16;
    for (int i = t; i < nAvail * K; i += 256) sX[i] = A[(size_t)nodeBase * K + i];
    __syncthreads();
    int d = t & 127;
    for (int ni = (t >> 7); ni < nAvail; ni += 2) {
        float acc = 0.f;
#pragma unroll
        for (int k = 0; k < K; ++k) acc += sX[ni * K + k] * sW[k * 128 + d];
        out[(size_t)(nodeBase + ni) * 128 + d] = __float2half(acc);
    }
}

// ------ CSR gather-aggregate (fp16 h) + self loop + bias + ReLU -----------
// one wave per node; lane owns half2 (2 dims); 16 gathers in flight.
__global__ __launch_bounds__(256) void agg_kernel(const __half* __restrict__ h,
                                                  const int* __restrict__ rowptr,
                                                  const int2* __restrict__ csr,
                                                  const float* __restrict__ dinv,
                                                  const float* __restrict__ bias,
                                                  float* __restrict__ out, int n_nodes) {
    int wave = threadIdx.x >> 6;
    int lane = threadIdx.x & 63;
    int node = blockIdx.x * 4 + wave;
    if (node >= n_nodes) return;
    int beg = rowptr[node];
    int end = rowptr[node + 1];
    float a0 = 0.f, a1 = 0.f;
    int e = beg;
    for (; e + 16 <= end; e += 16) {
        int2 p[16];
#pragma unroll
        for (int j = 0; j < 16; ++j) p[j] = csr[e + j];
        __half2 v[16];
#pragma unroll
        for (int j = 0; j < 16; ++j)
            v[j] = *(reinterpret_cast<const __half2*>(h + (size_t)p[j].x * HIDC) + lane);
#pragma unroll
        for (int j = 0; j < 16; ++j) {
            float c = __int_as_float(p[j].y);
            float2 f = __half22float2(v[j]);
            a0 += c * f.x; a1 += c * f.y;
        }
    }
    for (; e + 4 <= end; e += 4) {
        int2 p[4];
#pragma unroll
        for (int j = 0; j < 4; ++j) p[j] = csr[e + j];
        __half2 v[4];
#pragma unroll
        for (int j = 0; j < 4; ++j)
            v[j] = *(reinterpret_cast<const __half2*>(h + (size_t)p[j].x * HIDC) + lane);
#pragma unroll
        for (int j = 0; j < 4; ++j) {
            float c = __int_as_float(p[j].y);
            float2 f = __half22float2(v[j]);
            a0 += c * f.x; a1 += c * f.y;
        }
    }
    for (; e < end; ++e) {
        int2 p = csr[e];
        float c = __int_as_float(p.y);
        float2 f = __half22float2(*(reinterpret_cast<const __half2*>(h + (size_t)p.x * HIDC) + lane));
        a0 += c * f.x; a1 += c * f.y;
    }
    float di = dinv[node];
    float selfc = di * di;
    float2 fn = __half22float2(*(reinterpret_cast<const __half2*>(h + (size_t)node * HIDC) + lane));
    a0 += selfc * fn.x;
    a1 += selfc * fn.y;
    float2 bb = *(reinterpret_cast<const float2*>(bias) + lane);
    a0 = fmaxf(a0 + bb.x, 0.f);
    a1 = fmaxf(a1 + bb.y, 0.f);
    float2* op = reinterpret_cast<float2*>(out + (size_t)node * HIDC) + lane;
    *op = make_float2(a0, a1);
}

// ---------------- gptr[g] = lower_bound(batch, g) (batch is sorted) -------
__global__ void gptr_kernel(const int* __restrict__ batch, int* __restrict__ gptr,
                            int n_nodes, int n_graphs) {
    int g = blockIdx.x * blockDim.x + threadIdx.x;
    if (g > n_graphs) return;
    int lo = 0, hi = n_nodes;
    while (lo < hi) { int mid = (lo + hi) >> 1; if (batch[mid] < g) lo = mid + 1; else hi = mid; }
    gptr[g] = lo;
}

// ---------------- segmented pool: one wave per graph, no atomics ----------
__global__ __launch_bounds__(256) void pool_seg_kernel(const float* __restrict__ h,
                                                       const int* __restrict__ gptr,
                                                       float* __restrict__ pooled,
                                                       int n_graphs) {
    int wave = threadIdx.x >> 6;
    int lane = threadIdx.x & 63;
    int g = blockIdx.x * 4 + wave;
    if (g >= n_graphs) return;
    int beg = gptr[g], end = gptr[g + 1];
    float a0 = 0.f, a1 = 0.f;
    for (int i = beg; i < end; ++i) {
        float2 v = *(reinterpret_cast<const float2*>(h + (size_t)i * HIDC) + lane);
        a0 += v.x; a1 += v.y;
    }
    float2* op = reinterpret_cast<float2*>(pooled + (size_t)g * HIDC) + lane;
    *op = make_float2(a0, a1);
}

// ---------------- fused MLP head: relu(p@Wm1+bm1)@Wm2+bm2 -----------------
__global__ __launch_bounds__(128) void mlp_kernel(const float* __restrict__ pooled,
                                                  const float* __restrict__ Wm1,
                                                  const float* __restrict__ bm1,
                                                  const float* __restrict__ Wm2,
                                                  const float* __restrict__ bm2,
                                                  float* __restrict__ out, int out_dim) {
    int g = blockIdx.x;
    int t = threadIdx.x;
    __shared__ float row[128];
    __shared__ float z[128];
    row[t] = pooled[g * 128 + t];
    __syncthreads();
    float acc = bm1[t];
#pragma unroll 8
    for (int k = 0; k < 128; ++k) acc += row[k] * Wm1[k * 128 + t];
    z[t] = fmaxf(acc, 0.f);
    __syncthreads();
    if (t < out_dim) {
        float o = bm2[t];
#pragma unroll 8
        for (int k = 0; k < 128; ++k) o += z[k] * Wm2[k * out_dim + t];
        out[g * out_dim + t] = o;
    }
}

extern "C" void kernel_launch(void* const* d_in, const int* in_sizes, int n_in,
                              void* d_out, int out_size, void* d_ws, size_t ws_size,
                              hipStream_t stream) {
    const float* x   = (const float*)d_in[0];
    const int*   ei  = (const int*)d_in[1];
    const int*   bat = (const int*)d_in[2];
    const float* ea  = (const float*)d_in[3];
    const float* W1  = (const float*)d_in[4];
    const float* b1  = (const float*)d_in[5];
    const float* W2  = (const float*)d_in[6];
    const float* b2  = (const float*)d_in[7];
    const float* Wm1 = (const float*)d_in[8];
    const float* bm1 = (const float*)d_in[9];
    const float* Wm2 = (const float*)d_in[10];
    const float* bm2 = (const float*)d_in[11];
    float* out = (float*)d_out;

    const int N = in_sizes[2];           // 50000 nodes
    const int E = in_sizes[1] / 2;       // 1.6M edges
    const int N_GRAPHS = 512;
    const int OUT_DIM = out_size / N_GRAPHS;  // 10

    // workspace layout (all 256B-aligned)
    char* ws = (char*)d_ws;
    size_t off = 0;
    auto alloc = [&](size_t bytes) { char* p = ws + off; off += (bytes + 255) & ~size_t(255); return p; };
    __half* bufH    = (__half*)alloc((size_t)N * HIDC * 2);  // h1 then h2 (gathered, fp16)
    float*  bufB    = (float*)alloc((size_t)N * HIDC * 4);   // hr1 then hr2 (fp32)
    int2*   csr     = (int2*) alloc((size_t)E * 8);
    int*    rank    = (int*)  alloc((size_t)E * 4);
    unsigned long long* degcnt = (unsigned long long*)alloc((size_t)N * 8);
    float*  dinv    = (float*)alloc((size_t)N * 4);
    int*    rowptr  = (int*)  alloc((size_t)(N + 1) * 4);
    int*    blocksum= (int*)  alloc(1024);
    int*    blockoff= (int*)  alloc(1024);
    int*    gptr    = (int*)  alloc((size_t)(N_GRAPHS + 1) * 4);
    float*  pooled  = (float*)alloc((size_t)N_GRAPHS * HIDC * 4);

    const int B = 256;
    int gN = (N + B - 1) / B;            // 196 blocks
    int gE = (E + B - 1) / B;

    // 1. zero degcnt
    init_kernel<<<gN, B, 0, stream>>>(degcnt, N);
    // 2. hist: packed degree+count atomic, rank from returned old value
    hist_kernel<<<gE, B, 0, stream>>>(ei, ea, degcnt, rank, E);
    // 3a. dinv + block sums
    dinv_blocksum_kernel<<<gN, B, 0, stream>>>(degcnt, dinv, blocksum, N);
    // 3b. scan block sums
    scan_blocksums_kernel<<<1, 256, 0, stream>>>(blocksum, blockoff, gN);
    // 3c. rowptr
    rowptr_kernel<<<gN, B, 0, stream>>>(degcnt, blockoff, rowptr, N);
    // 4. CSR fill (atomic-free scatter)
    fill_kernel<<<gE, B, 0, stream>>>(ei, ea, dinv, rowptr, rank, csr, E);
    // 5. h1 = x @ W1  (fp16 out)
    gemm_tiled<64><<<(N + 15) / 16, 256, 0, stream>>>(x, W1, bufH, N);
    // 6. hr1 = relu(aggregate(h1) + b1)  (fp32)
    agg_kernel<<<(N + 3) / 4, 256, 0, stream>>>(bufH, rowptr, csr, dinv, b1, bufB, N);
    // 7. h2 = hr1 @ W2  (fp16 out)
    gemm_tiled<128><<<(N + 15) / 16, 256, 0, stream>>>(bufB, W2, bufH, N);
    // 8. hr2 = relu(aggregate(h2) + b2)  (fp32)
    agg_kernel<<<(N + 3) / 4, 256, 0, stream>>>(bufH, rowptr, csr, dinv, b2, bufB, N);
    // 9. gptr via binary search on sorted batch
    gptr_kernel<<<3, 256, 0, stream>>>(bat, gptr, N, N_GRAPHS);
    // 10. segmented pool (no atomics)
    pool_seg_kernel<<<(N_GRAPHS + 3) / 4, 256, 0, stream>>>(bufB, gptr, pooled, N_GRAPHS);
    // 11. MLP head
    mlp_kernel<<<N_GRAPHS, 128, 0, stream>>>(pooled, Wm1, bm1, Wm2, bm2, out, OUT_DIM);
}